// Round 5
// baseline (71.967 us; speedup 1.0000x reference)
//
#include <hip/hip_runtime.h>

#define H 512
#define W 512
#define NPIX (H * W)
#define BIG_I 1073741824   // 2^30
#define BIG_F 1.0e6f
#define INF30 1.0e30f

// ---- workspace layout ----
// [0, NPIX) int32       : lab  (union-find forest)
// [NPIX, 2*NPIX) float  : dist (row-pass result)
// then (64B aligned): Scal, Asoa[256], then lab2[NPIX] (final labels)
struct Scal {
  float soa;
  unsigned int min_bits;
  float cluster;
  int pad[5];
};

// ---- persistent cross-replay sync state (NOT in re-poisoned workspace) ----
// All monotonic: per launch, g_ticket +256, each g_tileflag +1; barrier
// counters +256 (or +0), so no per-launch re-init is ever needed.
__device__ unsigned g_ticket;
__device__ unsigned g_tileflag[256];
__device__ unsigned g_barM, g_barR, g_barC, g_doneS, g_doneD;

// Device-wide barrier for exactly 256 co-resident blocks (proven R3/R4).
__device__ __forceinline__ void gbar(unsigned* cnt, bool wait) {
  __syncthreads();
  if (threadIdx.x == 0) {
    __threadfence();
    unsigned old = atomicAdd(cnt, 1u);
    if (wait) {
      unsigned target = (old & ~255u) + 256u;
      while (__hip_atomic_load(cnt, __ATOMIC_RELAXED, __HIP_MEMORY_SCOPE_AGENT) < target)
        __builtin_amdgcn_s_sleep(1);
      __threadfence();
    }
  }
  __syncthreads();
}

// ================= union-find (min-index roots) =================
// Plain variants: LDS, or global AFTER a global barrier (all writes visible).
__device__ __forceinline__ int rep(int* lab, int v) {
  int cur = lab[v];
  if (cur == v) return v;
  int prev = v, next;
  while (cur > (next = lab[cur])) { lab[prev] = next; prev = cur; cur = next; }
  return cur;
}
__device__ __forceinline__ void unite(int* lab, int a, int b) {
  int ra = rep(lab, a), rb = rep(lab, b);
  while (ra != rb) {
    if (ra < rb) { int t = ra; ra = rb; rb = t; }
    int old = atomicCAS(&lab[ra], ra, rb);
    if (old == ra) break;
    ra = rep(lab, old);
    rb = rep(lab, rb);
  }
}
__device__ __forceinline__ int root_ph(int* lab, int v) {
  int p = lab[v];
  if (p == v) return v;
  int gp = lab[p];
  while (p != gp) {
    lab[v] = gp;     // benign race: gp is an ancestor of v
    v = p; p = gp; gp = lab[p];
  }
  return p;
}
// Agent-coherent variants for phase B' (chain walks may leave the acquired
// neighbor set; any value read is a valid same-set representative).
__device__ __forceinline__ int lda(int* p) {
  return __hip_atomic_load(p, __ATOMIC_RELAXED, __HIP_MEMORY_SCOPE_AGENT);
}
__device__ __forceinline__ int rep_bp(int* lab, int v) {
  int cur = lda(&lab[v]);
  if (cur == v) return v;
  int prev = v, next;
  while (cur > (next = lda(&lab[cur]))) { lab[prev] = next; prev = cur; cur = next; }
  return cur;
}
__device__ __forceinline__ void unite_bp(int* lab, int a, int b) {
  int ra = rep_bp(lab, a), rb = rep_bp(lab, b);
  while (ra != rb) {
    if (ra < rb) { int t = ra; ra = rb; rb = t; }
    int old = atomicCAS(&lab[ra], ra, rb);
    if (old == ra) break;
    ra = rep_bp(lab, old);
    rb = rep_bp(lab, rb);
  }
}
// run start column of bit c in mask (bit c must be set)
__device__ __forceinline__ int runstart(unsigned m, int c) {
  unsigned z = ~m & ((1u << c) - 1u);
  return z ? (32 - __clz((int)z)) : 0;
}

// ======================================================================
// Single fused kernel. Skip path: A (unconditional, overlaps the pts->img
// prologue chain) -> tile flags -> B'(per-tile border, neighbor-scoped
// sync) -> ONE global bar -> C'(flatten-first, then short root walks,
// cluster) -> done-counter finalize.
// Non-skip adds: lab2 write, barR, row DT, barC, col DT + finalize.
// Exact-identity shortcuts: !both -> fallback scalar everywhere;
// sl==el -> min_d == 0 exactly (start comp subset of DT zero set).
// ======================================================================
__global__ __launch_bounds__(256) void k_fused(
    const float* __restrict__ img, const int* __restrict__ pts,
    int* __restrict__ lab, int* __restrict__ lab2, float* __restrict__ dist,
    Scal* __restrict__ s, float* __restrict__ Asoa, float* __restrict__ out) {
  __shared__ union {
    struct { int uf[1024]; unsigned rmask[32]; float red[4]; } p1;
    struct { float laf[32][8]; float lbb[32][8]; float smin[4]; } p4;
  } sh;
  __shared__ int s_sl, s_el, s_skip;
  __shared__ float cred[4];

  const int t = threadIdx.x;
  const int b = blockIdx.x;
  const int tY = b >> 4, tX = b & 15;
  const int tileX = tX * 32, tileY = tY * 32;
  const int r = t >> 3, c0 = (t & 7) * 4;      // thread owns 4 px of tile-row r
  const float4 x4 = *(const float4*)(img + (tileY + r) * W + tileX + c0);

  // ---- prologue loads ISSUED here, consumed after phase A (latency hidden) ----
  const int p0 = pts[0] * W + pts[1];
  const int p1x = pts[2] * W + pts[3];
  const float r0 = img[p0], r1 = img[p1x];

  // launch epoch: 256 tickets/launch -> tk>>8 uniform within a launch
  unsigned ep1 = 0;
  if (t < 64) {
    unsigned tk = 0;
    if (t == 0) tk = atomicAdd(&g_ticket, 1u);
    tk = __shfl(tk, 0, 64);
    ep1 = (tk >> 8) + 1u;
  }

  // ---- phase A: per-tile (32x32) LDS CCL (run-based) + soa partial ----
  // Runs unconditionally (harmless in !both; keeps pts chain off critical path).
  int o[4];
  {
    float acc = 4.0f - (x4.x + x4.y + x4.z + x4.w);
    unsigned nib = (rintf(x4.x) > 0.5f ? 1u : 0u) | (rintf(x4.y) > 0.5f ? 2u : 0u)
                 | (rintf(x4.z) > 0.5f ? 4u : 0u) | (rintf(x4.w) > 0.5f ? 8u : 0u);
    unsigned m = nib << c0;                    // full row mask via OR over lanes 8r..8r+7
    m |= __shfl_xor(m, 1, 64);
    m |= __shfl_xor(m, 2, 64);
    m |= __shfl_xor(m, 4, 64);
    if ((t & 7) == 0) sh.p1.rmask[r] = m;
    unsigned startM = m & ~(m << 1);
    #pragma unroll
    for (int k = 0; k < 4; ++k) {              // init union-find at run starts only
      int c = c0 + k;
      if ((startM >> c) & 1u) sh.p1.uf[(r << 5) + c] = (r << 5) + c;
    }
    __syncthreads();
    if (r > 0) {
      unsigned ma = sh.p1.rmask[r - 1];
      unsigned upM = m & ma & (~(m << 1) | ~(ma << 1));
      unsigned dL  = startM & (ma << 1) & ~ma;
      unsigned dR  = (m & ~(m >> 1)) & (ma >> 1) & ~ma;
      #pragma unroll
      for (int k = 0; k < 4; ++k) {
        int c = c0 + k;
        int myS = (r << 5) + runstart(m, c);
        if ((upM >> c) & 1u) unite(sh.p1.uf, myS, ((r - 1) << 5) + runstart(ma, c));
        if ((dL  >> c) & 1u) unite(sh.p1.uf, myS, ((r - 1) << 5) + runstart(ma, c - 1));
        if ((dR  >> c) & 1u) unite(sh.p1.uf, myS, ((r - 1) << 5) + c + 1);
      }
    }
    __syncthreads();
    #pragma unroll
    for (int k = 0; k < 4; ++k) {
      int c = c0 + k;
      if ((m >> c) & 1u) {
        int rt = rep(sh.p1.uf, (r << 5) + runstart(m, c));
        o[k] = (tileY + (rt >> 5)) * W + tileX + (rt & 31);
      } else o[k] = BIG_I;
    }
    *(int4*)(lab + (tileY + r) * W + tileX + c0) = make_int4(o[0], o[1], o[2], o[3]);
    for (int off = 32; off; off >>= 1) acc += __shfl_down(acc, off, 64);
    if ((t & 63) == 0) sh.p1.red[t >> 6] = acc;
    __syncthreads();
    if (t == 0) {
      Asoa[b] = sh.p1.red[0] + sh.p1.red[1] + sh.p1.red[2] + sh.p1.red[3];
      __threadfence();                         // release: tile labels + Asoa
      __hip_atomic_store(&g_tileflag[b], ep1, __ATOMIC_RELAXED,
                         __HIP_MEMORY_SCOPE_AGENT);
    }
  }

  // ---- deferred prologue: uniform branch (loads already in flight) ----
  const bool both = (rintf(r0) > 0.5f) && (rintf(r1) > 0.5f);
  const float fb = (2.0f - (r0 + r1)) * 100.0f;
  if (!both) {                                 // uniform: flags released, no bars
    if (b == 0 && t == 0) { out[0] = fb; out[1] = fb; out[2] = fb; }
    return;
  }
  if (b == 0 && t == 0) {                      // published by barM's release
    s->min_bits = __float_as_uint(BIG_F);
    s->cluster = 0.0f;
  }

  // ---- phase B': per-tile border merge after neighbor-scoped sync ----
  // Block (tY,tX) owns the H-boundary below its tile and the V-boundary
  // right of its tile. Direct reads touch only {own,S,SW,W,E,N,NE}.
  if (t < 64) {
    const bool hasH = tY < 15, hasV = tX < 15;
    int nb = -1;
    if (t == 0 && hasH)            nb = b + 16;       // S
    if (t == 1 && hasH && tX > 0)  nb = b + 15;       // SW
    if (t == 2 && hasH && tX > 0)  nb = b - 1;        // W
    if (t == 3 && hasV)            nb = b + 1;        // E
    if (t == 4 && hasV && tY > 0)  nb = b - 16;       // N
    if (t == 5 && hasV && tY > 0)  nb = b - 15;       // NE
    if (nb >= 0) {                             // wave lockstep: lanes 6..63 wait too
      while (__hip_atomic_load(&g_tileflag[nb], __ATOMIC_RELAXED,
                               __HIP_MEMORY_SCOPE_AGENT) < ep1)
        __builtin_amdgcn_s_sleep(1);
    }
    __threadfence();                           // acquire neighbor tiles
    if (t < 32) {
      if (hasH) {                              // H boundary: row tileY+32
        const int j = tileX + t;
        const int p = (tileY + 32) * W + j, q = p - W;
        int a  = lab[p];
        int u0 = lab[q];
        int um = (j > 0)   ? lab[q - 1] : BIG_I;
        int up = (j < 511) ? lab[q + 1] : BIG_I;
        int a_prev = __shfl_up(a, 1, 64);
        if (t == 0) a_prev = (j > 0) ? lab[p - 1] : BIG_I;
        if (a != BIG_I) {
          if (um != BIG_I && a != a_prev) unite_bp(lab, a, um);
          if (u0 != BIG_I && u0 != um) unite_bp(lab, a, u0);
          if (up != BIG_I && up != u0 && !(u0 == BIG_I && up == um)) unite_bp(lab, a, up);
        }
      }
    } else {
      if (hasV) {                              // V boundary: col tileX+32
        const int il = t - 32;
        const int i = tileY + il;
        const int p = i * W + tileX + 32;
        int lp = lab[p], ll = lab[p - 1];
        int lpp = __shfl_up(lp, 1, 64);
        int llp = __shfl_up(ll, 1, 64);
        if (il == 0) {
          lpp = (i > 0) ? lab[p - W] : BIG_I;
          llp = (i > 0) ? lab[p - W - 1] : BIG_I;
        }
        bool fgp = lp != BIG_I, fgl = ll != BIG_I;
        if (fgp && fgl && !(lp == lpp && ll == llp)) unite_bp(lab, lp, ll);
        if (il != 0) {                         // il==0 diagonals covered by N's H pass
          if (fgp && llp != BIG_I && lp != lpp) unite_bp(lab, lp, llp);
          if (fgl && lpp != BIG_I && ll != llp) unite_bp(lab, ll, lpp);
        }
      }
    }
  }
  gbar(&g_barM, true);                         // the ONLY global bar (skip path)

  // ---- phase C': flatten FIRST (parallel forest compression), then the
  // (now short) p0/p1 root walks, then cluster sum.
  if (b == 60 && t >= 64 && t < 128) {         // soa reduce (off critical path)
    int l = t & 63;
    float a = Asoa[l] + Asoa[l + 64] + Asoa[l + 128] + Asoa[l + 192];
    for (int off = 32; off; off >>= 1) a += __shfl_down(a, off, 64);
    if (l == 0) s->soa = a;
  }
  int fin[4];
  {
    int psrc = -1, proot = -1;
    #pragma unroll
    for (int k = 0; k < 4; ++k) {              // flatten own px from registers
      if (o[k] == BIG_I) { fin[k] = BIG_I; continue; }
      if (o[k] == psrc) { fin[k] = proot; continue; }
      psrc = o[k];
      proot = root_ph(lab, o[k]);
      fin[k] = proot;
    }
  }
  if (t == 0) {                                // chains pre-compressed by flatten
    int e  = root_ph(lab, lab[p1x]);
    int s2 = root_ph(lab, lab[p0]);
    s_el = e; s_sl = s2; s_skip = (e == s2);
  }
  __syncthreads();
  const int slv = s_sl, elv = s_el;
  const bool skip = s_skip != 0;               // uniform across blocks
  float cv = 0.0f;
  if (fin[0] == slv) cv += x4.x;
  if (fin[1] == slv) cv += x4.y;
  if (fin[2] == slv) cv += x4.z;
  if (fin[3] == slv) cv += x4.w;
  for (int off = 32; off; off >>= 1) cv += __shfl_down(cv, off, 64);
  if ((t & 63) == 0) cred[t >> 6] = cv;
  __syncthreads();
  if (t == 0) {
    float tot = cred[0] + cred[1] + cred[2] + cred[3];
    if (tot != 0.0f) atomicAdd(&s->cluster, tot);
  }
  if (!skip)                                   // lab2 only consumed by DT path
    *(int4*)(lab2 + (tileY + r) * W + tileX + c0) = make_int4(fin[0], fin[1], fin[2], fin[3]);

  if (skip) {                                  // min_d == 0 exactly: finalize
    if (t == 0) {
      __threadfence();
      unsigned old = atomicAdd(&g_doneS, 1u);
      if ((old & 255u) == 255u) {              // last of this launch's 256
        __threadfence();                       // acquire others' cluster adds
        out[0] = fb;
        out[1] = 0.0f;                         // min_d * soa * 10 * soa == 0
        float cl = atomicAdd(&s->cluster, 0.0f);
        out[2] = cl * 90.0f;
      }
    }
    return;
  }

  // ================= non-skip: full DT path =================
  gbar(&g_barR, true);                         // lab2 complete
  if (t < 128) {                               // row min-plus scan (2 rows/block)
    int lane = t & 63;
    int row = b * 2 + (t >> 6);
    const int4* lp2 = (const int4*)(lab2 + row * W) + lane * 2;
    int4 a = lp2[0], bq = lp2[1];
    int v[8] = {a.x, a.y, a.z, a.w, bq.x, bq.y, bq.z, bq.w};
    float d[8];
    #pragma unroll
    for (int k = 0; k < 8; ++k) d[k] = (v[k] == elv) ? 0.0f : BIG_F;
    int j0 = lane * 8;
    float pf[8], sb[8];
    float m = INF30;
    #pragma unroll
    for (int k = 0; k < 8; ++k) { m = fminf(m, d[k] - (float)(j0 + k)); pf[k] = m; }
    float tf = m;
    m = INF30;
    #pragma unroll
    for (int k = 7; k >= 0; --k) { m = fminf(m, d[k] + (float)(j0 + k)); sb[k] = m; }
    float tb = m;
    float vv = tf;
    #pragma unroll
    for (int off = 1; off < 64; off <<= 1) {
      float u = __shfl_up(vv, off, 64);
      if (lane >= off) vv = fminf(vv, u);
    }
    float ef = __shfl_up(vv, 1, 64); if (lane == 0) ef = INF30;
    vv = tb;
    #pragma unroll
    for (int off = 1; off < 64; off <<= 1) {
      float u = __shfl_down(vv, off, 64);
      if (lane < 64 - off) vv = fminf(vv, u);
    }
    float eb = __shfl_down(vv, 1, 64); if (lane == 63) eb = INF30;
    float oo[8];
    #pragma unroll
    for (int k = 0; k < 8; ++k) {
      float j = (float)(j0 + k);
      oo[k] = fminf(j + fminf(ef, pf[k]), -j + fminf(eb, sb[k]));
    }
    float4* dp = (float4*)(dist + row * W) + lane * 2;
    dp[0] = make_float4(oo[0], oo[1], oo[2], oo[3]);
    dp[1] = make_float4(oo[4], oo[5], oo[6], oo[7]);
  }
  if (b >= 64) { gbar(&g_barC, false); return; }   // arrive-only
  gbar(&g_barC, true);

  // ---- column DT + masked min + finalize (64 blocks x 8 cols) ----
  {
    int sg = t >> 3, c = t & 7;                // 32 segments x 8 cols
    int j = b * 8 + c;
    int i0 = sg * 16;
    float rr[16];
    float fa = INF30, fbk = INF30;
    #pragma unroll
    for (int il = 0; il < 16; ++il) {
      rr[il] = dist[(i0 + il) * W + j];
      float fi = (float)(i0 + il);
      fa = fminf(fa, rr[il] - fi);
      fbk = fminf(fbk, rr[il] + fi);
    }
    sh.p4.laf[sg][c] = fa;
    sh.p4.lbb[sg][c] = fbk;
    __syncthreads();
    float cf = INF30, cb = INF30;
    #pragma unroll
    for (int bb = 0; bb < 32; ++bb) {
      if (bb < sg) cf = fminf(cf, sh.p4.laf[bb][c]);
      if (bb > sg) cb = fminf(cb, sh.p4.lbb[bb][c]);
    }
    float ff[16];
    float m = cf;
    #pragma unroll
    for (int il = 0; il < 16; ++il) {
      float fi = (float)(i0 + il);
      m = fminf(m, rr[il] - fi);
      ff[il] = fi + m;
    }
    m = cb;
    float dv = BIG_F;
    #pragma unroll
    for (int il = 15; il >= 0; --il) {         // final dist consumed in-register
      int pix = (i0 + il) * W + j;
      float fi = (float)(i0 + il);
      m = fminf(m, rr[il] + fi);
      float oo = fminf(ff[il], m - fi);
      if (lab2[pix] == slv) dv = fminf(dv, oo);
      if (pix == p0) dv = fminf(dv, oo);       // dist[p0] term, mask-independent
    }
    for (int off = 32; off; off >>= 1)
      dv = fminf(dv, __shfl_down(dv, off, 64));
    if ((t & 63) == 0) sh.p4.smin[t >> 6] = dv;
    __syncthreads();
    if (t == 0) {
      float mm = fminf(fminf(sh.p4.smin[0], sh.p4.smin[1]),
                       fminf(sh.p4.smin[2], sh.p4.smin[3]));
      atomicMin(&s->min_bits, __float_as_uint(mm));  // dist>=0: uint order == float
      __threadfence();
      unsigned old = atomicAdd(&g_doneD, 1u);
      if ((old & 63u) == 63u) {                // last of this launch's 64
        __threadfence();
        out[0] = fb;
        float min_d = __uint_as_float(atomicOr(&s->min_bits, 0u));
        float cl = atomicAdd(&s->cluster, 0.0f);
        float soa = s->soa;
        out[1] = min_d * soa * 10.0f * soa;
        out[2] = cl * 90.0f;
      }
    }
  }
}

extern "C" void kernel_launch(void* const* d_in, const int* in_sizes, int n_in,
                              void* d_out, int out_size, void* d_ws, size_t ws_size,
                              hipStream_t stream) {
  const float* img = (const float*)d_in[0] + 3 * NPIX;   // result_given[3,0]
  const int* pts = (const int*)d_in[1] + 3 * 4;          // points_given[3]
  float* out = (float*)d_out;

  int* lab = (int*)d_ws;
  float* dist = (float*)d_ws + NPIX;
  char* base = (char*)d_ws + (size_t)2 * NPIX * 4;
  Scal* s = (Scal*)base;
  float* Asoa = (float*)(base + 64);
  int* lab2 = (int*)(base + 64 + 1024);

  k_fused<<<256, 256, 0, stream>>>(img, pts, lab, lab2, dist, s, Asoa, out);
}

// Round 6
// 54.254 us; speedup vs baseline: 1.3265x; 1.3265x over previous
//
#include <hip/hip_runtime.h>

#define H 512
#define W 512
#define NPIX (H * W)
#define BIG_I 1073741824   // 2^30
#define BIG_F 1.0e6f
#define INF30 1.0e30f

// ---- workspace layout ----
// [0, NPIX) int32       : lab  (union-find forest)
// [NPIX, 2*NPIX) float  : dist (row-pass result)
// then (64B aligned): Scal, Asoa[256], then lab2[NPIX] (final labels)
struct Scal {
  float soa;
  unsigned int min_bits;
  float cluster;
  int pad[5];
};

// ---- persistent cross-replay sync state (NOT in re-poisoned workspace) ----
// All monotonic: per both-launch, g_ticket +256, each g_tileflag +1, each
// barrier counter +256 (or +0), so no per-launch re-init is ever needed.
__device__ unsigned g_ticket;
__device__ unsigned g_tileflag[256];
__device__ unsigned g_barM, g_barR, g_barC, g_doneS, g_doneD;

// Device-wide barrier for exactly 256 co-resident blocks (proven in R3).
__device__ __forceinline__ void gbar(unsigned* cnt, bool wait) {
  __syncthreads();
  if (threadIdx.x == 0) {
    __threadfence();
    unsigned old = atomicAdd(cnt, 1u);
    if (wait) {
      unsigned target = (old & ~255u) + 256u;
      while (__hip_atomic_load(cnt, __ATOMIC_RELAXED, __HIP_MEMORY_SCOPE_AGENT) < target)
        __builtin_amdgcn_s_sleep(1);
      __threadfence();
    }
  }
  __syncthreads();
}

// ================= union-find (min-index roots) =================
// Plain variants: LDS, or global AFTER a global barrier (all writes visible).
__device__ __forceinline__ int rep(int* lab, int v) {
  int cur = lab[v];
  if (cur == v) return v;
  int prev = v, next;
  while (cur > (next = lab[cur])) { lab[prev] = next; prev = cur; cur = next; }
  return cur;
}
__device__ __forceinline__ void unite(int* lab, int a, int b) {
  int ra = rep(lab, a), rb = rep(lab, b);
  while (ra != rb) {
    if (ra < rb) { int t = ra; ra = rb; rb = t; }
    int old = atomicCAS(&lab[ra], ra, rb);
    if (old == ra) break;
    ra = rep(lab, old);
    rb = rep(lab, rb);
  }
}
__device__ __forceinline__ int root_ph(int* lab, int v) {
  int p = lab[v];
  if (p == v) return v;
  int gp = lab[p];
  while (p != gp) {
    lab[v] = gp;     // benign race: gp is an ancestor of v
    v = p; p = gp; gp = lab[p];
  }
  return p;
}
// Agent-coherent variants: used in phase B', where chain walks can reach
// tiles outside the acquired neighbor set (plain loads could hit stale
// lines). Any value read is a valid same-set representative (links only
// move toward roots), so relaxed agent loads suffice.
__device__ __forceinline__ int lda(int* p) {
  return __hip_atomic_load(p, __ATOMIC_RELAXED, __HIP_MEMORY_SCOPE_AGENT);
}
__device__ __forceinline__ int rep_bp(int* lab, int v) {
  int cur = lda(&lab[v]);
  if (cur == v) return v;
  int prev = v, next;
  while (cur > (next = lda(&lab[cur]))) { lab[prev] = next; prev = cur; cur = next; }
  return cur;
}
__device__ __forceinline__ void unite_bp(int* lab, int a, int b) {
  int ra = rep_bp(lab, a), rb = rep_bp(lab, b);
  while (ra != rb) {
    if (ra < rb) { int t = ra; ra = rb; rb = t; }
    int old = atomicCAS(&lab[ra], ra, rb);
    if (old == ra) break;
    ra = rep_bp(lab, old);
    rb = rep_bp(lab, rb);
  }
}
// run start column of bit c in mask (bit c must be set)
__device__ __forceinline__ int runstart(unsigned m, int c) {
  unsigned z = ~m & ((1u << c) - 1u);
  return z ? (32 - __clz((int)z)) : 0;
}

// ======================================================================
// Single fused kernel. Skip path: A -> tile flags -> B'(per-tile border)
// -> ONE global bar -> C'(register-resident flatten+cluster) -> done.
// Non-skip adds: lab2 write, barR, row DT, barC, col DT + finalize.
// Exact-identity shortcuts: !both -> fallback scalar everywhere;
// sl==el -> min_d == 0 exactly (start comp subset of DT zero set).
// ======================================================================
__global__ __launch_bounds__(256) void k_fused(
    const float* __restrict__ img, const int* __restrict__ pts,
    int* __restrict__ lab, int* __restrict__ lab2, float* __restrict__ dist,
    Scal* __restrict__ s, float* __restrict__ Asoa, float* __restrict__ out) {
  __shared__ union {
    struct { int uf[1024]; unsigned rmask[32]; float red[4]; } p1;
    struct { float laf[32][8]; float lbb[32][8]; float smin[4]; } p4;
  } sh;
  __shared__ int s_sl, s_el, s_skip;
  __shared__ float cred[4];

  const int t = threadIdx.x;
  const int b = blockIdx.x;
  const int tY = b >> 4, tX = b & 15;
  const int tileX = tX * 32, tileY = tY * 32;
  const int r = t >> 3, c0 = (t & 7) * 4;      // thread owns 4 px of tile-row r
  const float4 x4 = *(const float4*)(img + (tileY + r) * W + tileX + c0);

  // ---- phase 0: uniform scalar prologue (4 scalar loads per block) ----
  const int p0 = pts[0] * W + pts[1];
  const int p1x = pts[2] * W + pts[3];
  const float r0 = img[p0], r1 = img[p1x];
  const bool both = (rintf(r0) > 0.5f) && (rintf(r1) > 0.5f);
  const float fb = (2.0f - (r0 + r1)) * 100.0f;
  if (!both) {                                 // uniform: no flags, no bars
    if (b == 0 && t == 0) { out[0] = fb; out[1] = fb; out[2] = fb; }
    return;
  }
  // launch epoch: 256 tickets/both-launch -> tk>>8 uniform within a launch
  unsigned ep1 = 0;
  if (t < 64) {
    unsigned tk = 0;
    if (t == 0) tk = atomicAdd(&g_ticket, 1u);
    tk = __shfl(tk, 0, 64);
    ep1 = (tk >> 8) + 1u;
  }
  if (b == 0 && t == 0) {                      // published by barM's release
    s->min_bits = __float_as_uint(BIG_F);
    s->cluster = 0.0f;
  }

  // ---- phase A: per-tile (32x32) LDS CCL (run-based) + soa partial ----
  int o[4];
  {
    float acc = 4.0f - (x4.x + x4.y + x4.z + x4.w);
    unsigned nib = (rintf(x4.x) > 0.5f ? 1u : 0u) | (rintf(x4.y) > 0.5f ? 2u : 0u)
                 | (rintf(x4.z) > 0.5f ? 4u : 0u) | (rintf(x4.w) > 0.5f ? 8u : 0u);
    unsigned m = nib << c0;                    // full row mask via OR over lanes 8r..8r+7
    m |= __shfl_xor(m, 1, 64);
    m |= __shfl_xor(m, 2, 64);
    m |= __shfl_xor(m, 4, 64);
    if ((t & 7) == 0) sh.p1.rmask[r] = m;
    unsigned startM = m & ~(m << 1);
    #pragma unroll
    for (int k = 0; k < 4; ++k) {              // init union-find at run starts only
      int c = c0 + k;
      if ((startM >> c) & 1u) sh.p1.uf[(r << 5) + c] = (r << 5) + c;
    }
    __syncthreads();
    if (r > 0) {
      unsigned ma = sh.p1.rmask[r - 1];
      unsigned upM = m & ma & (~(m << 1) | ~(ma << 1));
      unsigned dL  = startM & (ma << 1) & ~ma;
      unsigned dR  = (m & ~(m >> 1)) & (ma >> 1) & ~ma;
      #pragma unroll
      for (int k = 0; k < 4; ++k) {
        int c = c0 + k;
        int myS = (r << 5) + runstart(m, c);
        if ((upM >> c) & 1u) unite(sh.p1.uf, myS, ((r - 1) << 5) + runstart(ma, c));
        if ((dL  >> c) & 1u) unite(sh.p1.uf, myS, ((r - 1) << 5) + runstart(ma, c - 1));
        if ((dR  >> c) & 1u) unite(sh.p1.uf, myS, ((r - 1) << 5) + c + 1);
      }
    }
    __syncthreads();
    #pragma unroll
    for (int k = 0; k < 4; ++k) {
      int c = c0 + k;
      if ((m >> c) & 1u) {
        int rt = rep(sh.p1.uf, (r << 5) + runstart(m, c));
        o[k] = (tileY + (rt >> 5)) * W + tileX + (rt & 31);
      } else o[k] = BIG_I;
    }
    *(int4*)(lab + (tileY + r) * W + tileX + c0) = make_int4(o[0], o[1], o[2], o[3]);
    for (int off = 32; off; off >>= 1) acc += __shfl_down(acc, off, 64);
    if ((t & 63) == 0) sh.p1.red[t >> 6] = acc;
    __syncthreads();
    if (t == 0) {
      Asoa[b] = sh.p1.red[0] + sh.p1.red[1] + sh.p1.red[2] + sh.p1.red[3];
      __threadfence();                         // release: tile labels + Asoa
      __hip_atomic_store(&g_tileflag[b], ep1, __ATOMIC_RELAXED,
                         __HIP_MEMORY_SCOPE_AGENT);
    }
  }

  // ---- phase B': per-tile border merge after neighbor-scoped sync ----
  // Block (tY,tX) owns the H-boundary below its tile and the V-boundary
  // right of its tile. Direct reads touch only {own,S,SW,W,E,N,NE}.
  if (t < 64) {
    const bool hasH = tY < 15, hasV = tX < 15;
    int nb = -1;
    if (t == 0 && hasH)            nb = b + 16;       // S
    if (t == 1 && hasH && tX > 0)  nb = b + 15;       // SW
    if (t == 2 && hasH && tX > 0)  nb = b - 1;        // W
    if (t == 3 && hasV)            nb = b + 1;        // E
    if (t == 4 && hasV && tY > 0)  nb = b - 16;       // N
    if (t == 5 && hasV && tY > 0)  nb = b - 15;       // NE
    if (nb >= 0) {
      while (__hip_atomic_load(&g_tileflag[nb], __ATOMIC_RELAXED,
                               __HIP_MEMORY_SCOPE_AGENT) < ep1)
        __builtin_amdgcn_s_sleep(1);
    }
    __threadfence();                           // acquire neighbor tiles
    if (t < 32) {
      if (hasH) {                              // H boundary: row tileY+32
        const int j = tileX + t;
        const int p = (tileY + 32) * W + j, q = p - W;
        int a  = lab[p];
        int u0 = lab[q];
        int um = (j > 0)   ? lab[q - 1] : BIG_I;
        int up = (j < 511) ? lab[q + 1] : BIG_I;
        int a_prev = __shfl_up(a, 1, 64);
        if (t == 0) a_prev = (j > 0) ? lab[p - 1] : BIG_I;
        if (a != BIG_I) {
          if (um != BIG_I && a != a_prev) unite_bp(lab, a, um);
          if (u0 != BIG_I && u0 != um) unite_bp(lab, a, u0);
          if (up != BIG_I && up != u0 && !(u0 == BIG_I && up == um)) unite_bp(lab, a, up);
        }
      }
    } else {
      if (hasV) {                              // V boundary: col tileX+32
        const int il = t - 32;
        const int i = tileY + il;
        const int p = i * W + tileX + 32;
        int lp = lab[p], ll = lab[p - 1];
        int lpp = __shfl_up(lp, 1, 64);
        int llp = __shfl_up(ll, 1, 64);
        if (il == 0) {
          lpp = (i > 0) ? lab[p - W] : BIG_I;
          llp = (i > 0) ? lab[p - W - 1] : BIG_I;
        }
        bool fgp = lp != BIG_I, fgl = ll != BIG_I;
        if (fgp && fgl && !(lp == lpp && ll == llp)) unite_bp(lab, lp, ll);
        if (il != 0) {                         // il==0 diagonals covered by N's H pass
          if (fgp && llp != BIG_I && lp != lpp) unite_bp(lab, lp, llp);
          if (fgl && lpp != BIG_I && ll != llp) unite_bp(lab, ll, lpp);
        }
      }
    }
  }
  gbar(&g_barM, true);                         // the ONLY global bar (skip path)

  // ---- phase C': register-resident flatten + cluster (+ skip decision) ----
  if (t == 0) {                                // roots final + deterministic
    int e  = root_ph(lab, lab[p1x]);
    int s2 = root_ph(lab, lab[p0]);
    s_el = e; s_sl = s2; s_skip = (e == s2);
  }
  if (b == 60 && t >= 64 && t < 128) {         // soa reduce (overlaps flatten)
    int l = t & 63;
    float a = Asoa[l] + Asoa[l + 64] + Asoa[l + 128] + Asoa[l + 192];
    for (int off = 32; off; off >>= 1) a += __shfl_down(a, off, 64);
    if (l == 0) s->soa = a;
  }
  int fin[4];
  {
    int psrc = -1, proot = -1;
    #pragma unroll
    for (int k = 0; k < 4; ++k) {              // flatten own px from registers
      if (o[k] == BIG_I) { fin[k] = BIG_I; continue; }
      if (o[k] == psrc) { fin[k] = proot; continue; }
      psrc = o[k];
      proot = root_ph(lab, o[k]);
      fin[k] = proot;
    }
  }
  __syncthreads();
  const int slv = s_sl, elv = s_el;
  const bool skip = s_skip != 0;               // uniform across blocks
  float cv = 0.0f;
  if (fin[0] == slv) cv += x4.x;
  if (fin[1] == slv) cv += x4.y;
  if (fin[2] == slv) cv += x4.z;
  if (fin[3] == slv) cv += x4.w;
  for (int off = 32; off; off >>= 1) cv += __shfl_down(cv, off, 64);
  if ((t & 63) == 0) cred[t >> 6] = cv;
  __syncthreads();
  if (t == 0) {
    float tot = cred[0] + cred[1] + cred[2] + cred[3];
    if (tot != 0.0f) atomicAdd(&s->cluster, tot);
  }
  if (!skip)                                   // lab2 only consumed by DT path
    *(int4*)(lab2 + (tileY + r) * W + tileX + c0) = make_int4(fin[0], fin[1], fin[2], fin[3]);

  if (skip) {                                  // min_d == 0 exactly: finalize
    if (t == 0) {
      __threadfence();
      unsigned old = atomicAdd(&g_doneS, 1u);
      if ((old & 255u) == 255u) {              // last of this launch's 256
        __threadfence();                       // acquire others' cluster adds
        out[0] = fb;
        out[1] = 0.0f;                         // min_d * soa * 10 * soa == 0
        float cl = atomicAdd(&s->cluster, 0.0f);
        out[2] = cl * 90.0f;
      }
    }
    return;
  }

  // ================= non-skip: full DT path =================
  gbar(&g_barR, true);                         // lab2 complete
  if (t < 128) {                               // row min-plus scan (2 rows/block)
    int lane = t & 63;
    int row = b * 2 + (t >> 6);
    const int4* lp2 = (const int4*)(lab2 + row * W) + lane * 2;
    int4 a = lp2[0], bq = lp2[1];
    int v[8] = {a.x, a.y, a.z, a.w, bq.x, bq.y, bq.z, bq.w};
    float d[8];
    #pragma unroll
    for (int k = 0; k < 8; ++k) d[k] = (v[k] == elv) ? 0.0f : BIG_F;
    int j0 = lane * 8;
    float pf[8], sb[8];
    float m = INF30;
    #pragma unroll
    for (int k = 0; k < 8; ++k) { m = fminf(m, d[k] - (float)(j0 + k)); pf[k] = m; }
    float tf = m;
    m = INF30;
    #pragma unroll
    for (int k = 7; k >= 0; --k) { m = fminf(m, d[k] + (float)(j0 + k)); sb[k] = m; }
    float tb = m;
    float vv = tf;
    #pragma unroll
    for (int off = 1; off < 64; off <<= 1) {
      float u = __shfl_up(vv, off, 64);
      if (lane >= off) vv = fminf(vv, u);
    }
    float ef = __shfl_up(vv, 1, 64); if (lane == 0) ef = INF30;
    vv = tb;
    #pragma unroll
    for (int off = 1; off < 64; off <<= 1) {
      float u = __shfl_down(vv, off, 64);
      if (lane < 64 - off) vv = fminf(vv, u);
    }
    float eb = __shfl_down(vv, 1, 64); if (lane == 63) eb = INF30;
    float oo[8];
    #pragma unroll
    for (int k = 0; k < 8; ++k) {
      float j = (float)(j0 + k);
      oo[k] = fminf(j + fminf(ef, pf[k]), -j + fminf(eb, sb[k]));
    }
    float4* dp = (float4*)(dist + row * W) + lane * 2;
    dp[0] = make_float4(oo[0], oo[1], oo[2], oo[3]);
    dp[1] = make_float4(oo[4], oo[5], oo[6], oo[7]);
  }
  if (b >= 64) { gbar(&g_barC, false); return; }   // arrive-only
  gbar(&g_barC, true);

  // ---- column DT + masked min + finalize (64 blocks x 8 cols) ----
  {
    int sg = t >> 3, c = t & 7;                // 32 segments x 8 cols
    int j = b * 8 + c;
    int i0 = sg * 16;
    float rr[16];
    float fa = INF30, fbk = INF30;
    #pragma unroll
    for (int il = 0; il < 16; ++il) {
      rr[il] = dist[(i0 + il) * W + j];
      float fi = (float)(i0 + il);
      fa = fminf(fa, rr[il] - fi);
      fbk = fminf(fbk, rr[il] + fi);
    }
    sh.p4.laf[sg][c] = fa;
    sh.p4.lbb[sg][c] = fbk;
    __syncthreads();
    float cf = INF30, cb = INF30;
    #pragma unroll
    for (int bb = 0; bb < 32; ++bb) {
      if (bb < sg) cf = fminf(cf, sh.p4.laf[bb][c]);
      if (bb > sg) cb = fminf(cb, sh.p4.lbb[bb][c]);
    }
    float ff[16];
    float m = cf;
    #pragma unroll
    for (int il = 0; il < 16; ++il) {
      float fi = (float)(i0 + il);
      m = fminf(m, rr[il] - fi);
      ff[il] = fi + m;
    }
    m = cb;
    float dv = BIG_F;
    #pragma unroll
    for (int il = 15; il >= 0; --il) {         // final dist consumed in-register
      int pix = (i0 + il) * W + j;
      float fi = (float)(i0 + il);
      m = fminf(m, rr[il] + fi);
      float oo = fminf(ff[il], m - fi);
      if (lab2[pix] == slv) dv = fminf(dv, oo);
      if (pix == p0) dv = fminf(dv, oo);       // dist[p0] term, mask-independent
    }
    for (int off = 32; off; off >>= 1)
      dv = fminf(dv, __shfl_down(dv, off, 64));
    if ((t & 63) == 0) sh.p4.smin[t >> 6] = dv;
    __syncthreads();
    if (t == 0) {
      float mm = fminf(fminf(sh.p4.smin[0], sh.p4.smin[1]),
                       fminf(sh.p4.smin[2], sh.p4.smin[3]));
      atomicMin(&s->min_bits, __float_as_uint(mm));  // dist>=0: uint order == float
      __threadfence();
      unsigned old = atomicAdd(&g_doneD, 1u);
      if ((old & 63u) == 63u) {                // last of this launch's 64
        __threadfence();
        out[0] = fb;
        float min_d = __uint_as_float(atomicOr(&s->min_bits, 0u));
        float cl = atomicAdd(&s->cluster, 0.0f);
        float soa = s->soa;
        out[1] = min_d * soa * 10.0f * soa;
        out[2] = cl * 90.0f;
      }
    }
  }
}

extern "C" void kernel_launch(void* const* d_in, const int* in_sizes, int n_in,
                              void* d_out, int out_size, void* d_ws, size_t ws_size,
                              hipStream_t stream) {
  const float* img = (const float*)d_in[0] + 3 * NPIX;   // result_given[3,0]
  const int* pts = (const int*)d_in[1] + 3 * 4;          // points_given[3]
  float* out = (float*)d_out;

  int* lab = (int*)d_ws;
  float* dist = (float*)d_ws + NPIX;
  char* base = (char*)d_ws + (size_t)2 * NPIX * 4;
  Scal* s = (Scal*)base;
  float* Asoa = (float*)(base + 64);
  int* lab2 = (int*)(base + 64 + 1024);

  k_fused<<<256, 256, 0, stream>>>(img, pts, lab, lab2, dist, s, Asoa, out);
}